// Round 8
// baseline (545.431 us; speedup 1.0000x reference)
//
#include <hip/hip_runtime.h>
#include <cstdint>

typedef __bf16 bf16;
typedef __attribute__((ext_vector_type(8))) __bf16 bf16x8;
typedef __attribute__((ext_vector_type(4))) __bf16 bf16x4;
typedef __attribute__((ext_vector_type(4))) float f32x4;
typedef __attribute__((ext_vector_type(8))) unsigned short u16x8;

#define AS1C(p) ((const __attribute__((address_space(1))) void*)(p))
#define AS3(p)  ((__attribute__((address_space(3))) void*)(p))

__device__ __forceinline__ float gelu_exact(float v) {
    return 0.5f * v * (1.0f + erff(v * 0.7071067811865476f));
}

// ---------------------------------------------------------------------------
// Weight transpose + fp32->bf16 convert: w [K][N] fp32 -> wt [N][K] bf16
// ---------------------------------------------------------------------------
__global__ __launch_bounds__(256, 1) void wtrans_kernel(
    const float* __restrict__ w, bf16* __restrict__ wt, int K, int N)
{
    __shared__ float tile[64][65];
    const int k0 = blockIdx.y * 64, n0 = blockIdx.x * 64;
    const int tid = threadIdx.x;
    {
        const int kl = tid >> 2, nc = (tid & 3) * 16;
        #pragma unroll
        for (int i = 0; i < 4; ++i) {
            const float4 v = *(const float4*)&w[(size_t)(k0 + kl) * N + n0 + nc + i * 4];
            tile[kl][nc + i * 4 + 0] = v.x;
            tile[kl][nc + i * 4 + 1] = v.y;
            tile[kl][nc + i * 4 + 2] = v.z;
            tile[kl][nc + i * 4 + 3] = v.w;
        }
    }
    __syncthreads();
    {
        const int nl = tid >> 2, kc = (tid & 3) * 16;
        #pragma unroll
        for (int i = 0; i < 4; ++i) {
            bf16x4 o4;
            o4[0] = (bf16)tile[kc + i * 4 + 0][nl];
            o4[1] = (bf16)tile[kc + i * 4 + 1][nl];
            o4[2] = (bf16)tile[kc + i * 4 + 2][nl];
            o4[3] = (bf16)tile[kc + i * 4 + 3][nl];
            *(bf16x4*)&wt[(size_t)(n0 + nl) * K + k0 + kc + i * 4] = o4;
        }
    }
}

__global__ void bias3_kernel(const float* __restrict__ a, const float* __restrict__ b,
                             const float* __restrict__ c, float* __restrict__ o)
{
    const int i = blockIdx.x * 256 + threadIdx.x;
    o[i] = (i < 1024) ? a[i] : (i < 2048 ? b[i - 1024] : c[i - 2048]);
}

// ---------------------------------------------------------------------------
// LayerNorm over rows of 1024 fp32 -> bf16. grid 8192 x 256
// ---------------------------------------------------------------------------
__global__ __launch_bounds__(256, 1) void ln_kernel(
    const float* __restrict__ x, const float* __restrict__ gw,
    const float* __restrict__ bw, bf16* __restrict__ out)
{
    const int row = blockIdx.x, tid = threadIdx.x;
    const float4 v = *(const float4*)&x[(size_t)row * 1024 + tid * 4];
    float s = v.x + v.y + v.z + v.w;
    float q = v.x * v.x + v.y * v.y + v.z * v.z + v.w * v.w;
    #pragma unroll
    for (int off = 32; off > 0; off >>= 1) {
        s += __shfl_xor(s, off);
        q += __shfl_xor(q, off);
    }
    __shared__ float red[8];
    if ((tid & 63) == 0) { red[tid >> 6] = s; red[4 + (tid >> 6)] = q; }
    __syncthreads();
    s = red[0] + red[1] + red[2] + red[3];
    q = red[4] + red[5] + red[6] + red[7];
    const float mu = s * (1.f / 1024.f);
    const float rs = rsqrtf(q * (1.f / 1024.f) - mu * mu + 1e-5f);
    const float4 gg = *(const float4*)&gw[tid * 4];
    const float4 bb = *(const float4*)&bw[tid * 4];
    bf16x4 o4;
    o4[0] = (bf16)((v.x - mu) * rs * gg.x + bb.x);
    o4[1] = (bf16)((v.y - mu) * rs * gg.y + bb.y);
    o4[2] = (bf16)((v.z - mu) * rs * gg.z + bb.z);
    o4[3] = (bf16)((v.w - mu) * rs * gg.w + bb.w);
    *(bf16x4*)&out[(size_t)row * 1024 + tid * 4] = o4;
}

// ---------------------------------------------------------------------------
// GEMM v8: register-pipelined single-phase K-loop.
// 512 threads (8 waves = 2/SIMD), BM=256, BN=128, per-wave 64x64, BK=32.
// LDS: 4 buffers x 24KB = 96KB. Depth-3 staging (stage t+3 at phase t,
// 3 global_load_lds/thread), counted vmcnt(6/3/0) BEFORE barrier1 (cross-
// wave publish). Phase t: read tile t+1's fragments into the ALTERNATE
// register set (no WAR vs tile t's in-flight MFMA cluster), counted
// lgkmcnt(8), 16 MFMA on current set. MFMA pipe drain overlaps next
// phase's LDS reads. Never vmcnt(0)/lgkmcnt(0) mid-loop.
// Swizzle (64B rows): read lb ^= ((lb>>6)&3)<<4; source chunk-permute
// (tid&3)^((tid>>2)&3); linear global_load_lds dest.
// ---------------------------------------------------------------------------
template<int EPI>
__global__ __launch_bounds__(512, 2) void gemm_v8_kernel(
    const bf16* __restrict__ A, const bf16* __restrict__ BT,
    const float* __restrict__ bias, const float* __restrict__ res,
    void* __restrict__ out, int M, int N, int K)
{
    constexpr int ABYTES = 256 * 64;   // 16384
    constexpr int BUFB = 384 * 64;     // 24576
    extern __shared__ char lds[];

    const int tid = threadIdx.x;
    const int lane = tid & 63, wid = tid >> 6;
    const int wr = wid >> 1, wc = wid & 1;
    const int j = lane & 15, g = lane >> 4;
    const int srow = tid >> 2;
    const int skc = (((tid & 3) ^ ((tid >> 2) & 3)) << 3);  // source k-chunk (elems)

    const int nbn = N >> 7;
    const int nwg = (M >> 8) * nbn;
    const int wg = (blockIdx.x & 7) * (nwg >> 3) + (blockIdx.x >> 3);
    const int bm = (wg / nbn) << 8;
    const int bn = (wg % nbn) << 7;

    const int NT = K >> 5;

    auto stage = [&](int t) {
        char* obuf = lds + (t & 3) * BUFB;
        const int k0 = t << 5;
        const bf16* sA0 = A + (size_t)(bm + srow) * K + k0 + skc;
        __builtin_amdgcn_global_load_lds(AS1C(sA0), AS3(obuf + tid * 16), 16, 0, 0);
        const bf16* sA1 = A + (size_t)(bm + 128 + srow) * K + k0 + skc;
        __builtin_amdgcn_global_load_lds(AS1C(sA1), AS3(obuf + 8192 + tid * 16), 16, 0, 0);
        const bf16* sB = BT + (size_t)(bn + srow) * K + k0 + skc;
        __builtin_amdgcn_global_load_lds(AS1C(sB), AS3(obuf + ABYTES + tid * 16), 16, 0, 0);
    };
    auto rdA = [&](char* buf, int mf) {
        const int R = wr * 64 + mf * 16 + j;
        uint32_t lb = (uint32_t)(R * 64 + g * 16);
        lb ^= ((lb >> 6) & 3u) << 4;
        return *(const bf16x8*)(buf + lb);
    };
    auto rdB = [&](char* buf, int nf) {
        const int R = wc * 64 + nf * 16 + j;
        uint32_t lb = (uint32_t)(R * 64 + g * 16);
        lb ^= ((lb >> 6) & 3u) << 4;
        return *(const bf16x8*)(buf + ABYTES + lb);
    };

    f32x4 acc[4][4] = {};

    // prologue: stage tiles 0..2, publish tile 0, read its fragments
    stage(0); stage(1); stage(2);
    asm volatile("s_waitcnt vmcnt(6)" ::: "memory");
    __builtin_amdgcn_s_barrier();
    __builtin_amdgcn_sched_barrier(0);
    bf16x8 afX[4], bfX[4], afY[4], bfY[4];
    #pragma unroll
    for (int mf = 0; mf < 4; ++mf) afX[mf] = rdA(lds, mf);
    #pragma unroll
    for (int nf = 0; nf < 4; ++nf) bfX[nf] = rdB(lds, nf);

    auto body = [&](int t, bf16x8 (&afc)[4], bf16x8 (&bfc)[4],
                    bf16x8 (&afn)[4], bf16x8 (&bfn)[4]) {
        if (t + 3 < NT) stage(t + 3);
        if (t + 1 < NT) {
            if (t + 3 < NT)      asm volatile("s_waitcnt vmcnt(6)" ::: "memory");
            else if (t + 2 < NT) asm volatile("s_waitcnt vmcnt(3)" ::: "memory");
            else                 asm volatile("s_waitcnt vmcnt(0)" ::: "memory");
        }
        __builtin_amdgcn_s_barrier();
        __builtin_amdgcn_sched_barrier(0);
        if (t + 1 < NT) {
            char* nbuf = lds + ((t + 1) & 3) * BUFB;
            #pragma unroll
            for (int mf = 0; mf < 4; ++mf) afn[mf] = rdA(nbuf, mf);
            #pragma unroll
            for (int nf = 0; nf < 4; ++nf) bfn[nf] = rdB(nbuf, nf);
            asm volatile("s_waitcnt lgkmcnt(8)" ::: "memory");
        } else {
            asm volatile("s_waitcnt lgkmcnt(0)" ::: "memory");
        }
        __builtin_amdgcn_sched_barrier(0);
        __builtin_amdgcn_s_setprio(1);
        #pragma unroll
        for (int mf = 0; mf < 4; ++mf)
            #pragma unroll
            for (int nf = 0; nf < 4; ++nf)
                acc[mf][nf] = __builtin_amdgcn_mfma_f32_16x16x32_bf16(
                    afc[mf], bfc[nf], acc[mf][nf], 0, 0, 0);
        __builtin_amdgcn_s_setprio(0);
        __builtin_amdgcn_s_barrier();
    };

    for (int t = 0; t < NT; t += 2) {
        body(t,     afX, bfX, afY, bfY);
        body(t + 1, afY, bfY, afX, bfX);
    }

    const int row0 = bm + wr * 64;
    const int col0 = bn + wc * 64;
    #pragma unroll
    for (int nf = 0; nf < 4; ++nf) {
        const int col = col0 + nf * 16 + j;
        const float bs = bias[col];
        #pragma unroll
        for (int mf = 0; mf < 4; ++mf) {
            #pragma unroll
            for (int r = 0; r < 4; ++r) {
                const int row = row0 + mf * 16 + g * 4 + r;
                float v = acc[mf][nf][r] + bs;
                if constexpr (EPI == 2 || EPI == 3) v = gelu_exact(v);
                if constexpr (EPI == 1 || EPI == 3) {
                    v += res[(size_t)row * N + col];
                    ((float*)out)[(size_t)row * N + col] = v;
                } else {
                    ((bf16*)out)[(size_t)row * N + col] = (bf16)v;
                }
            }
        }
    }
}

// ---------------------------------------------------------------------------
// Flash attention v5 (unchanged from round 7).
// ---------------------------------------------------------------------------
__device__ __forceinline__ void attn_iter(
    int c, const bf16* __restrict__ Kp, const bf16* __restrict__ Vp,
    uint32_t (&vTu)[4][64][36],
    bf16x8 (&kf)[4][2], bf16x8 (&kfn)[4][2],
    const bf16x8& qf0, const bf16x8& qf1,
    f32x4 (&o)[4], float& mrun, float& lsum,
    int kp, int d0, int jperm, int g, int j)
{
    const f32x4 zero = {0.f, 0.f, 0.f, 0.f};
    const bool pfv = (c + 2 < 16);
    const bool pfk = (c + 1 < 16);

    u16x8 r0, r1;
    if (pfv) {
        const size_t vb = (size_t)((c + 2) * 64 + kp) * 3072 + d0;
        r0 = *(const u16x8*)&Vp[vb];
        r1 = *(const u16x8*)&Vp[vb + 3072];
    }

    f32x4 s[4];
    #pragma unroll
    for (int t = 0; t < 4; ++t) {
        s[t] = __builtin_amdgcn_mfma_f32_16x16x32_bf16(kf[t][0], qf0, zero, 0, 0, 0);
        s[t] = __builtin_amdgcn_mfma_f32_16x16x32_bf16(kf[t][1], qf1, s[t], 0, 0, 0);
    }

    if (pfk) {
        #pragma unroll
        for (int t = 0; t < 4; ++t) {
            const int key = (c + 1) * 64 + (t >> 1) * 32 + jperm + (t & 1) * 4;
            kfn[t][0] = *(const bf16x8*)&Kp[(size_t)key * 3072 + g * 8];
            kfn[t][1] = *(const bf16x8*)&Kp[(size_t)key * 3072 + 32 + g * 8];
        }
    }

    float cur = fmaxf(fmaxf(s[0][0], s[0][1]), fmaxf(s[0][2], s[0][3]));
    #pragma unroll
    for (int t = 1; t < 4; ++t)
        cur = fmaxf(cur, fmaxf(fmaxf(s[t][0], s[t][1]), fmaxf(s[t][2], s[t][3])));
    cur = fmaxf(cur, __shfl_xor(cur, 16));
    cur = fmaxf(cur, __shfl_xor(cur, 32));

    if (!__all(cur - mrun <= 8.0f)) {
        const float mnew = fmaxf(mrun, cur);
        const float alpha = __expf(mrun - mnew);
        float al[4];
        #pragma unroll
        for (int r = 0; r < 4; ++r) al[r] = __shfl(alpha, g * 4 + r);
        #pragma unroll
        for (int dt = 0; dt < 4; ++dt)
            #pragma unroll
            for (int r = 0; r < 4; ++r) o[dt][r] *= al[r];
        lsum *= alpha;
        mrun = mnew;
    }
    float ps = 0.f;
    #pragma unroll
    for (int t = 0; t < 4; ++t)
        #pragma unroll
        for (int r = 0; r < 4; ++r) {
            const float p = __expf(s[t][r] - mrun);
            s[t][r] = p;
            ps += p;
        }
    lsum += ps;

    bf16x8 pa0, pa1;
    #pragma unroll
    for (int r = 0; r < 4; ++r) {
        pa0[r]     = (bf16)s[0][r];
        pa0[4 + r] = (bf16)s[1][r];
        pa1[r]     = (bf16)s[2][r];
        pa1[4 + r] = (bf16)s[3][r];
    }

    if (pfv) {
        const int wb = (c + 2) & 3;
        #pragma unroll
        for (int i = 0; i < 8; ++i)
            vTu[wb][d0 + i][kp >> 1] = (uint32_t)r0[i] | ((uint32_t)r1[i] << 16);
    }

    const int rb = c & 3;
    #pragma unroll
    for (int dt = 0; dt < 4; ++dt) {
        const bf16* vrow = (const bf16*)&vTu[rb][dt * 16 + j][0];
        const bf16x8 vb0 = *(const bf16x8*)(vrow + g * 8);
        const bf16x8 vb1 = *(const bf16x8*)(vrow + 32 + g * 8);
        o[dt] = __builtin_amdgcn_mfma_f32_16x16x32_bf16(pa0, vb0, o[dt], 0, 0, 0);
        o[dt] = __builtin_amdgcn_mfma_f32_16x16x32_bf16(pa1, vb1, o[dt], 0, 0, 0);
    }
}

__global__ __launch_bounds__(256, 1) void attn_kernel(
    const bf16* __restrict__ qkv, bf16* __restrict__ attn, int bh_base)
{
    const int tid = threadIdx.x;
    const int lane = tid & 63, wid = tid >> 6;
    const int j = lane & 15, g = lane >> 4;

    const int lin = blockIdx.x + blockIdx.y * 16;
    const int virt = (lin & 7) * 128 + (lin >> 3);
    const int bh = bh_base + (virt >> 4), qt = virt & 15;
    const int b = bh >> 4, h = bh & 15;
    const int q0 = qt * 64 + wid * 16;

    const bf16* Qp = qkv + (size_t)b * 1024 * 3072 + h * 64;
    const bf16* Kp = Qp + 1024;
    const bf16* Vp = Qp + 2048;

    __shared__ __attribute__((aligned(16))) uint32_t vTu[4][64][36];

    const int kp = (tid & 31) * 2;
    const int d0 = (tid >> 5) * 8;
    #pragma unroll
    for (int pb = 0; pb < 2; ++pb) {
        const u16x8 r0 = *(const u16x8*)&Vp[(size_t)(pb * 64 + kp) * 3072 + d0];
        const u16x8 r1 = *(const u16x8*)&Vp[(size_t)(pb * 64 + kp + 1) * 3072 + d0];
        #pragma unroll
        for (int i = 0; i < 8; ++i)
            vTu[pb][d0 + i][kp >> 1] = (uint32_t)r0[i] | ((uint32_t)r1[i] << 16);
    }

    bf16x8 qf0 = *(const bf16x8*)&Qp[(size_t)(q0 + j) * 3072 + g * 8];
    bf16x8 qf1 = *(const bf16x8*)&Qp[(size_t)(q0 + j) * 3072 + 32 + g * 8];
    #pragma unroll
    for (int e = 0; e < 8; ++e) {
        qf0[e] = (bf16)((float)qf0[e] * 0.03125f);
        qf1[e] = (bf16)((float)qf1[e] * 0.03125f);
    }

    const int jperm = (j >> 2) * 8 + (j & 3);

    f32x4 o[4] = {};
    float mrun = -1e30f, lsum = 0.f;

    bf16x8 kfA[4][2], kfB[4][2];
    #pragma unroll
    for (int t = 0; t < 4; ++t) {
        const int key = (t >> 1) * 32 + jperm + (t & 1) * 4;
        kfA[t][0] = *(const bf16x8*)&Kp[(size_t)key * 3072 + g * 8];
        kfA[t][1] = *(const bf16x8*)&Kp[(size_t)key * 3072 + 32 + g * 8];
    }

    asm volatile("s_waitcnt lgkmcnt(0)" ::: "memory");
    __builtin_amdgcn_s_barrier();

    for (int cc = 0; cc < 16; cc += 2) {
        attn_iter(cc,     Kp, Vp, vTu, kfA, kfB, qf0, qf1, o, mrun, lsum, kp, d0, jperm, g, j);
        attn_iter(cc + 1, Kp, Vp, vTu, kfB, kfA, qf0, qf1, o, mrun, lsum, kp, d0, jperm, g, j);
        asm volatile("s_waitcnt lgkmcnt(0)" ::: "memory");
        __builtin_amdgcn_sched_barrier(0);
        __builtin_amdgcn_s_barrier();
    }

    lsum += __shfl_xor(lsum, 16);
    lsum += __shfl_xor(lsum, 32);
    float inv[4];
    #pragma unroll
    for (int r = 0; r < 4; ++r) inv[r] = 1.0f / __shfl(lsum, g * 4 + r);
    #pragma unroll
    for (int dt = 0; dt < 4; ++dt)
        #pragma unroll
        for (int r = 0; r < 4; ++r)
            attn[(size_t)(b * 1024 + q0 + g * 4 + r) * 1024 + h * 64 + dt * 16 + j] =
                (bf16)(o[dt][r] * inv[r]);
}

// ---------------------------------------------------------------------------
extern "C" void kernel_launch(void* const* d_in, const int* in_sizes, int n_in,
                              void* d_out, int out_size, void* d_ws, size_t ws_size,
                              hipStream_t stream)
{
    const float* x    = (const float*)d_in[0];
    const float* ln1g = (const float*)d_in[1];
    const float* ln1b = (const float*)d_in[2];
    const float* wq   = (const float*)d_in[3];
    const float* bq   = (const float*)d_in[4];
    const float* wk   = (const float*)d_in[5];
    const float* bk   = (const float*)d_in[6];
    const float* wv   = (const float*)d_in[7];
    const float* bv   = (const float*)d_in[8];
    const float* wo   = (const float*)d_in[9];
    const float* bo   = (const float*)d_in[10];
    const float* ln2g = (const float*)d_in[11];
    const float* ln2b = (const float*)d_in[12];
    const float* w1   = (const float*)d_in[13];
    const float* b1   = (const float*)d_in[14];
    const float* w2   = (const float*)d_in[15];
    const float* b2   = (const float*)d_in[16];

    char* ws = (char*)d_ws;
    bf16* wqkvT = (bf16*)ws;  ws += (size_t)3072 * 1024 * 2;
    bf16* woT   = (bf16*)ws;  ws += (size_t)1024 * 1024 * 2;
    bf16* w1T   = (bf16*)ws;  ws += (size_t)4096 * 1024 * 2;
    bf16* w2T   = (bf16*)ws;  ws += (size_t)1024 * 4096 * 2;
    float* bqkv = (float*)ws; ws += (size_t)3072 * 4;
    bf16* h     = (bf16*)ws;  ws += (size_t)8192 * 1024 * 2;
    bf16* qkv   = (bf16*)ws;  ws += (size_t)8192 * 3072 * 2;
    bf16* attn  = (bf16*)ws;  ws += (size_t)8192 * 1024 * 2;
    float* outf = (float*)ws; ws += (size_t)8192 * 1024 * 4;
    bf16* m1    = (bf16*)ws;  ws += (size_t)8192 * 4096 * 2;

    (void)hipFuncSetAttribute((const void*)gemm_v8_kernel<0>,
                              hipFuncAttributeMaxDynamicSharedMemorySize, 98304);
    (void)hipFuncSetAttribute((const void*)gemm_v8_kernel<1>,
                              hipFuncAttributeMaxDynamicSharedMemorySize, 98304);
    (void)hipFuncSetAttribute((const void*)gemm_v8_kernel<2>,
                              hipFuncAttributeMaxDynamicSharedMemorySize, 98304);
    (void)hipFuncSetAttribute((const void*)gemm_v8_kernel<3>,
                              hipFuncAttributeMaxDynamicSharedMemorySize, 98304);

    wtrans_kernel<<<dim3(16, 16), 256, 0, stream>>>(wq, wqkvT,                   1024, 1024);
    wtrans_kernel<<<dim3(16, 16), 256, 0, stream>>>(wk, wqkvT + 1024 * 1024,     1024, 1024);
    wtrans_kernel<<<dim3(16, 16), 256, 0, stream>>>(wv, wqkvT + 2 * 1024 * 1024, 1024, 1024);
    wtrans_kernel<<<dim3(16, 16), 256, 0, stream>>>(wo, woT, 1024, 1024);
    wtrans_kernel<<<dim3(64, 16), 256, 0, stream>>>(w1, w1T, 1024, 4096);
    wtrans_kernel<<<dim3(16, 64), 256, 0, stream>>>(w2, w2T, 4096, 1024);
    bias3_kernel<<<12, 256, 0, stream>>>(bq, bk, bv, bqkv);

    // LN1
    ln_kernel<<<8192, 256, 0, stream>>>(x, ln1g, ln1b, h);
    // QKV projection: 32 x 24 = 768 blocks
    gemm_v8_kernel<0><<<768, 512, 98304, stream>>>(h, wqkvT, bqkv, nullptr, qkv, 8192, 3072, 1024);
    // attention (2 dispatches for profiler visibility)
    attn_kernel<<<dim3(16, 64), 256, 0, stream>>>(qkv, attn, 0);
    attn_kernel<<<dim3(16, 64), 256, 0, stream>>>(qkv, attn, 64);
    // O projection + bias + residual(x): 32 x 8 = 256 blocks
    gemm_v8_kernel<1><<<256, 512, 98304, stream>>>(attn, woT, bo, x, outf, 8192, 1024, 1024);
    // LN2
    ln_kernel<<<8192, 256, 0, stream>>>(outf, ln2g, ln2b, h);
    // MLP1: 32 x 32 = 1024 blocks
    gemm_v8_kernel<2><<<1024, 512, 98304, stream>>>(h, w1T, b1, nullptr, m1, 8192, 4096, 1024);
    // MLP2: 32 x 8 = 256 blocks, K=4096
    gemm_v8_kernel<3><<<256, 512, 98304, stream>>>(m1, w2T, b2, outf, (float*)d_out, 8192, 1024, 4096);
}

// Round 9
// 449.916 us; speedup vs baseline: 1.2123x; 1.2123x over previous
//
#include <hip/hip_runtime.h>
#include <cstdint>

typedef __bf16 bf16;
typedef __attribute__((ext_vector_type(8))) __bf16 bf16x8;
typedef __attribute__((ext_vector_type(4))) __bf16 bf16x4;
typedef __attribute__((ext_vector_type(4))) float f32x4;
typedef __attribute__((ext_vector_type(8))) unsigned short u16x8;

#define AS1C(p) ((const __attribute__((address_space(1))) void*)(p))
#define AS3(p)  ((__attribute__((address_space(3))) void*)(p))

__device__ __forceinline__ float gelu_exact(float v) {
    return 0.5f * v * (1.0f + erff(v * 0.7071067811865476f));
}

// ---------------------------------------------------------------------------
// Weight transpose + fp32->bf16 convert: w [K][N] fp32 -> wt [N][K] bf16
// ---------------------------------------------------------------------------
__global__ __launch_bounds__(256, 1) void wtrans_kernel(
    const float* __restrict__ w, bf16* __restrict__ wt, int K, int N)
{
    __shared__ float tile[64][65];
    const int k0 = blockIdx.y * 64, n0 = blockIdx.x * 64;
    const int tid = threadIdx.x;
    {
        const int kl = tid >> 2, nc = (tid & 3) * 16;
        #pragma unroll
        for (int i = 0; i < 4; ++i) {
            const float4 v = *(const float4*)&w[(size_t)(k0 + kl) * N + n0 + nc + i * 4];
            tile[kl][nc + i * 4 + 0] = v.x;
            tile[kl][nc + i * 4 + 1] = v.y;
            tile[kl][nc + i * 4 + 2] = v.z;
            tile[kl][nc + i * 4 + 3] = v.w;
        }
    }
    __syncthreads();
    {
        const int nl = tid >> 2, kc = (tid & 3) * 16;
        #pragma unroll
        for (int i = 0; i < 4; ++i) {
            bf16x4 o4;
            o4[0] = (bf16)tile[kc + i * 4 + 0][nl];
            o4[1] = (bf16)tile[kc + i * 4 + 1][nl];
            o4[2] = (bf16)tile[kc + i * 4 + 2][nl];
            o4[3] = (bf16)tile[kc + i * 4 + 3][nl];
            *(bf16x4*)&wt[(size_t)(n0 + nl) * K + k0 + kc + i * 4] = o4;
        }
    }
}

__global__ void bias3_kernel(const float* __restrict__ a, const float* __restrict__ b,
                             const float* __restrict__ c, float* __restrict__ o)
{
    const int i = blockIdx.x * 256 + threadIdx.x;
    o[i] = (i < 1024) ? a[i] : (i < 2048 ? b[i - 1024] : c[i - 2048]);
}

// ---------------------------------------------------------------------------
// LayerNorm over rows of 1024 fp32 -> bf16. grid 8192 x 256
// ---------------------------------------------------------------------------
__global__ __launch_bounds__(256, 1) void ln_kernel(
    const float* __restrict__ x, const float* __restrict__ gw,
    const float* __restrict__ bw, bf16* __restrict__ out)
{
    const int row = blockIdx.x, tid = threadIdx.x;
    const float4 v = *(const float4*)&x[(size_t)row * 1024 + tid * 4];
    float s = v.x + v.y + v.z + v.w;
    float q = v.x * v.x + v.y * v.y + v.z * v.z + v.w * v.w;
    #pragma unroll
    for (int off = 32; off > 0; off >>= 1) {
        s += __shfl_xor(s, off);
        q += __shfl_xor(q, off);
    }
    __shared__ float red[8];
    if ((tid & 63) == 0) { red[tid >> 6] = s; red[4 + (tid >> 6)] = q; }
    __syncthreads();
    s = red[0] + red[1] + red[2] + red[3];
    q = red[4] + red[5] + red[6] + red[7];
    const float mu = s * (1.f / 1024.f);
    const float rs = rsqrtf(q * (1.f / 1024.f) - mu * mu + 1e-5f);
    const float4 gg = *(const float4*)&gw[tid * 4];
    const float4 bb = *(const float4*)&bw[tid * 4];
    bf16x4 o4;
    o4[0] = (bf16)((v.x - mu) * rs * gg.x + bb.x);
    o4[1] = (bf16)((v.y - mu) * rs * gg.y + bb.y);
    o4[2] = (bf16)((v.z - mu) * rs * gg.z + bb.z);
    o4[3] = (bf16)((v.w - mu) * rs * gg.w + bb.w);
    *(bf16x4*)&out[(size_t)row * 1024 + tid * 4] = o4;
}

// ---------------------------------------------------------------------------
// GEMM v7 (restored verbatim — best measured GEMM this session).
// 512 threads (8 waves, 2/SIMD), BM=256, BN=128, per-wave 64x64, BK=64.
// 3 buffers x 48KB, depth-2 prefetch, end-of-tile vmcnt(6) counted.
// ---------------------------------------------------------------------------
template<int EPI>
__global__ __launch_bounds__(512, 2) void gemm_v7_kernel(
    const bf16* __restrict__ A, const bf16* __restrict__ BT,
    const float* __restrict__ bias, const float* __restrict__ res,
    void* __restrict__ out, int M, int N, int K)
{
    constexpr int ABYTES = 256 * 128;        // 32768
    constexpr int BUFB = 384 * 128;          // 49152
    extern __shared__ char lds[];

    const int tid = threadIdx.x;
    const int lane = tid & 63, wid = tid >> 6;
    const int wr = wid >> 1, wc = wid & 1;
    const int j = lane & 15, g = lane >> 4;
    const int skc = ((tid & 7) ^ ((tid >> 4) & 7)) << 3;   // source k-chunk (elems)

    const int nbn = N >> 7;
    const int nwg = (M >> 8) * nbn;
    const int bid = blockIdx.x;
    const int wg = (bid & 7) * (nwg >> 3) + (bid >> 3);
    const int bm = (wg / nbn) << 8;
    const int bn = (wg % nbn) << 7;

    auto stage = [&](int k0, char* obuf) {
        #pragma unroll
        for (int ga = 0; ga < 4; ++ga) {
            const bf16* src = A + (size_t)(bm + ga * 64 + (tid >> 3)) * K + k0 + skc;
            __builtin_amdgcn_global_load_lds(AS1C(src), AS3(obuf + ga * 8192 + tid * 16), 16, 0, 0);
        }
        #pragma unroll
        for (int gb = 0; gb < 2; ++gb) {
            const bf16* src = BT + (size_t)(bn + gb * 64 + (tid >> 3)) * K + k0 + skc;
            __builtin_amdgcn_global_load_lds(AS1C(src), AS3(obuf + ABYTES + gb * 8192 + tid * 16), 16, 0, 0);
        }
    };

    f32x4 acc[4][4] = {};
    const int NT = K >> 6;

    stage(0, lds);
    stage(64, lds + BUFB);
    asm volatile("s_waitcnt vmcnt(6)" ::: "memory");
    __builtin_amdgcn_s_barrier();

    int cur = 0;
    for (int t = 0; t < NT; ++t) {
        char* buf = lds + cur * BUFB;
        const int nxt2 = (cur >= 1) ? cur - 1 : 2;

        // ---- phase 0: A frags (8 reads, hoisted) + B frags 0,1; stage t+2 ----
        bf16x8 af[4][2], bfr[2][2];
        #pragma unroll
        for (int mf = 0; mf < 4; ++mf)
            #pragma unroll
            for (int ks = 0; ks < 2; ++ks) {
                const int R = wr * 64 + mf * 16 + j;
                uint32_t lb = (uint32_t)(R * 128 + ks * 64 + g * 16);
                lb ^= (lb >> 4) & 0x70u;
                af[mf][ks] = *(const bf16x8*)(buf + lb);
            }
        #pragma unroll
        for (int nf = 0; nf < 2; ++nf)
            #pragma unroll
            for (int ks = 0; ks < 2; ++ks) {
                const int R = wc * 64 + nf * 16 + j;
                uint32_t lb = (uint32_t)(R * 128 + ks * 64 + g * 16);
                lb ^= (lb >> 4) & 0x70u;
                bfr[nf][ks] = *(const bf16x8*)(buf + ABYTES + lb);
            }
        if (t + 2 < NT) stage((t + 2) << 6, lds + nxt2 * BUFB);
        __builtin_amdgcn_s_barrier();
        asm volatile("s_waitcnt lgkmcnt(0)" ::: "memory");
        __builtin_amdgcn_sched_barrier(0);
        __builtin_amdgcn_s_setprio(1);
        #pragma unroll
        for (int mf = 0; mf < 4; ++mf)
            #pragma unroll
            for (int nf = 0; nf < 2; ++nf)
                #pragma unroll
                for (int ks = 0; ks < 2; ++ks)
                    acc[mf][nf] = __builtin_amdgcn_mfma_f32_16x16x32_bf16(
                        af[mf][ks], bfr[nf][ks], acc[mf][nf], 0, 0, 0);
        __builtin_amdgcn_s_setprio(0);
        __builtin_amdgcn_s_barrier();

        // ---- phase 1: B frags 2,3; counted vmcnt at tile end ----
        bf16x8 bfr2[2][2];
        #pragma unroll
        for (int nf = 0; nf < 2; ++nf)
            #pragma unroll
            for (int ks = 0; ks < 2; ++ks) {
                const int R = wc * 64 + (2 + nf) * 16 + j;
                uint32_t lb = (uint32_t)(R * 128 + ks * 64 + g * 16);
                lb ^= (lb >> 4) & 0x70u;
                bfr2[nf][ks] = *(const bf16x8*)(buf + ABYTES + lb);
            }
        __builtin_amdgcn_s_barrier();
        asm volatile("s_waitcnt lgkmcnt(0)" ::: "memory");
        __builtin_amdgcn_sched_barrier(0);
        __builtin_amdgcn_s_setprio(1);
        #pragma unroll
        for (int mf = 0; mf < 4; ++mf)
            #pragma unroll
            for (int nf = 0; nf < 2; ++nf)
                #pragma unroll
                for (int ks = 0; ks < 2; ++ks)
                    acc[mf][2 + nf] = __builtin_amdgcn_mfma_f32_16x16x32_bf16(
                        af[mf][ks], bfr2[nf][ks], acc[mf][2 + nf], 0, 0, 0);
        __builtin_amdgcn_s_setprio(0);
        if (t + 2 < NT) asm volatile("s_waitcnt vmcnt(6)" ::: "memory");
        else            asm volatile("s_waitcnt vmcnt(0)" ::: "memory");
        __builtin_amdgcn_s_barrier();

        cur = (cur == 2) ? 0 : cur + 1;
    }

    const int row0 = bm + wr * 64;
    const int col0 = bn + wc * 64;
    #pragma unroll
    for (int nf = 0; nf < 4; ++nf) {
        const int col = col0 + nf * 16 + j;
        const float bs = bias[col];
        #pragma unroll
        for (int mf = 0; mf < 4; ++mf) {
            #pragma unroll
            for (int r = 0; r < 4; ++r) {
                const int row = row0 + mf * 16 + g * 4 + r;
                float v = acc[mf][nf][r] + bs;
                if constexpr (EPI == 2 || EPI == 3) v = gelu_exact(v);
                if constexpr (EPI == 1 || EPI == 3) {
                    v += res[(size_t)row * N + col];
                    ((float*)out)[(size_t)row * N + col] = v;
                } else {
                    ((bf16*)out)[(size_t)row * N + col] = (bf16)v;
                }
            }
        }
    }
}

// ---------------------------------------------------------------------------
// Flash attention v6: TWO independent q-tiles per wave (rows q0, q0+64).
// Doubles per-wave ILP (independent QK^T/softmax/PV chains); K fragments
// and LDS V reads shared between the two tiles. 4 V-buffers (race-free
// window), barrier every 2 iters. Block = 4 waves x 2x16 rows = 128 rows.
// ---------------------------------------------------------------------------
__global__ __launch_bounds__(256, 1) void attn_kernel(
    const bf16* __restrict__ qkv, bf16* __restrict__ attn, int bh_base)
{
    const int tid = threadIdx.x;
    const int lane = tid & 63, wid = tid >> 6;
    const int j = lane & 15, g = lane >> 4;

    // 512 blocks/dispatch: 8 q-pairs x 64 bh; XCD swizzle keeps one bh's
    // blocks on one XCD for K/V L2 reuse.
    const int lin = blockIdx.x + blockIdx.y * 8;
    const int virt = (lin & 7) * 64 + (lin >> 3);
    const int bh = bh_base + (virt >> 3), qp = virt & 7;
    const int b = bh >> 4, h = bh & 15;
    const int q0a = qp * 128 + wid * 16;
    const int q0b = q0a + 64;

    const bf16* Qp = qkv + (size_t)b * 1024 * 3072 + h * 64;
    const bf16* Kp = Qp + 1024;
    const bf16* Vp = Qp + 2048;

    __shared__ __attribute__((aligned(16))) uint32_t vTu[4][64][36];

    const int kp = (tid & 31) * 2;
    const int d0 = (tid >> 5) * 8;
    #pragma unroll
    for (int pb = 0; pb < 2; ++pb) {
        const u16x8 r0 = *(const u16x8*)&Vp[(size_t)(pb * 64 + kp) * 3072 + d0];
        const u16x8 r1 = *(const u16x8*)&Vp[(size_t)(pb * 64 + kp + 1) * 3072 + d0];
        #pragma unroll
        for (int i = 0; i < 8; ++i)
            vTu[pb][d0 + i][kp >> 1] = (uint32_t)r0[i] | ((uint32_t)r1[i] << 16);
    }

    // Q fragments for both tiles (scale 1/32 folded in, exact in bf16)
    bf16x8 qa0 = *(const bf16x8*)&Qp[(size_t)(q0a + j) * 3072 + g * 8];
    bf16x8 qa1 = *(const bf16x8*)&Qp[(size_t)(q0a + j) * 3072 + 32 + g * 8];
    bf16x8 qb0 = *(const bf16x8*)&Qp[(size_t)(q0b + j) * 3072 + g * 8];
    bf16x8 qb1 = *(const bf16x8*)&Qp[(size_t)(q0b + j) * 3072 + 32 + g * 8];
    #pragma unroll
    for (int e = 0; e < 8; ++e) {
        qa0[e] = (bf16)((float)qa0[e] * 0.03125f);
        qa1[e] = (bf16)((float)qa1[e] * 0.03125f);
        qb0[e] = (bf16)((float)qb0[e] * 0.03125f);
        qb1[e] = (bf16)((float)qb1[e] * 0.03125f);
    }

    const int jperm = (j >> 2) * 8 + (j & 3);

    f32x4 oa[4] = {}, ob[4] = {};
    float mra = -1e30f, lsa = 0.f;
    float mrb = -1e30f, lsb = 0.f;

    bf16x8 kfA[4][2], kfB[4][2];
    #pragma unroll
    for (int t = 0; t < 4; ++t) {
        const int key = (t >> 1) * 32 + jperm + (t & 1) * 4;
        kfA[t][0] = *(const bf16x8*)&Kp[(size_t)key * 3072 + g * 8];
        kfA[t][1] = *(const bf16x8*)&Kp[(size_t)key * 3072 + 32 + g * 8];
    }

    asm volatile("s_waitcnt lgkmcnt(0)" ::: "memory");
    __builtin_amdgcn_s_barrier();

    auto softmax = [&](f32x4 (&s)[4], float& mrun, float& lsum, f32x4 (&o)[4]) {
        float cur = fmaxf(fmaxf(s[0][0], s[0][1]), fmaxf(s[0][2], s[0][3]));
        #pragma unroll
        for (int t = 1; t < 4; ++t)
            cur = fmaxf(cur, fmaxf(fmaxf(s[t][0], s[t][1]), fmaxf(s[t][2], s[t][3])));
        cur = fmaxf(cur, __shfl_xor(cur, 16));
        cur = fmaxf(cur, __shfl_xor(cur, 32));
        if (!__all(cur - mrun <= 8.0f)) {       // defer-max (THR=8)
            const float mnew = fmaxf(mrun, cur);
            const float alpha = __expf(mrun - mnew);
            float al[4];
            #pragma unroll
            for (int r = 0; r < 4; ++r) al[r] = __shfl(alpha, g * 4 + r);
            #pragma unroll
            for (int dt = 0; dt < 4; ++dt)
                #pragma unroll
                for (int r = 0; r < 4; ++r) o[dt][r] *= al[r];
            lsum *= alpha;
            mrun = mnew;
        }
        float ps = 0.f;
        #pragma unroll
        for (int t = 0; t < 4; ++t)
            #pragma unroll
            for (int r = 0; r < 4; ++r) {
                const float p = __expf(s[t][r] - mrun);
                s[t][r] = p;
                ps += p;
            }
        lsum += ps;
    };

    auto iter = [&](int c, bf16x8 (&kf)[4][2], bf16x8 (&kfn)[4][2]) {
        const f32x4 zero = {0.f, 0.f, 0.f, 0.f};
        const bool pfv = (c + 2 < 16);
        const bool pfk = (c + 1 < 16);

        u16x8 r0, r1;
        if (pfv) {
            const size_t vb = (size_t)((c + 2) * 64 + kp) * 3072 + d0;
            r0 = *(const u16x8*)&Vp[vb];
            r1 = *(const u16x8*)&Vp[vb + 3072];
        }

        // QK^T for both tiles (independent chains, shared K fragments)
        f32x4 sa[4], sb[4];
        #pragma unroll
        for (int t = 0; t < 4; ++t) {
            sa[t] = __builtin_amdgcn_mfma_f32_16x16x32_bf16(kf[t][0], qa0, zero, 0, 0, 0);
            sb[t] = __builtin_amdgcn_mfma_f32_16x16x32_bf16(kf[t][0], qb0, zero, 0, 0, 0);
            sa[t] = __builtin_amdgcn_mfma_f32_16x16x32_bf16(kf[t][1], qa1, sa[t], 0, 0, 0);
            sb[t] = __builtin_amdgcn_mfma_f32_16x16x32_bf16(kf[t][1], qb1, sb[t], 0, 0, 0);
        }

        if (pfk) {
            #pragma unroll
            for (int t = 0; t < 4; ++t) {
                const int key = (c + 1) * 64 + (t >> 1) * 32 + jperm + (t & 1) * 4;
                kfn[t][0] = *(const bf16x8*)&Kp[(size_t)key * 3072 + g * 8];
                kfn[t][1] = *(const bf16x8*)&Kp[(size_t)key * 3072 + 32 + g * 8];
            }
        }

        softmax(sa, mra, lsa, oa);
        softmax(sb, mrb, lsb, ob);

        bf16x8 paa0, paa1, pab0, pab1;
        #pragma unroll
        for (int r = 0; r < 4; ++r) {
            paa0[r]     = (bf16)sa[0][r];
            paa0[4 + r] = (bf16)sa[1][r];
            paa1[r]     = (bf16)sa[2][r];
            paa1[4 + r] = (bf16)sa[3][r];
            pab0[r]     = (bf16)sb[0][r];
            pab0[4 + r] = (bf16)sb[1][r];
            pab1[r]     = (bf16)sb[2][r];
            pab1[4 + r] = (bf16)sb[3][r];
        }

        if (pfv) {
            const int wb = (c + 2) & 3;
            #pragma unroll
            for (int i = 0; i < 8; ++i)
                vTu[wb][d0 + i][kp >> 1] = (uint32_t)r0[i] | ((uint32_t)r1[i] << 16);
        }

        const int rb = c & 3;
        #pragma unroll
        for (int dt = 0; dt < 4; ++dt) {
            const bf16* vrow = (const bf16*)&vTu[rb][dt * 16 + j][0];
            const bf16x8 vb0 = *(const bf16x8*)(vrow + g * 8);
            const bf16x8 vb1 = *(const bf16x8*)(vrow + 32 + g * 8);
            oa[dt] = __builtin_amdgcn_mfma_f32_16x16x32_bf16(paa0, vb0, oa[dt], 0, 0, 0);
            ob[dt] = __builtin_amdgcn_mfma_f32_16x16x32_bf16(pab0, vb0, ob[dt], 0, 0, 0);
            oa[dt] = __builtin_amdgcn_mfma_f32_16x16x32_bf16(paa1, vb1, oa[dt], 0, 0, 0);
            ob[dt] = __builtin_amdgcn_mfma_f32_16x16x32_bf16(pab1, vb1, ob[dt], 0, 0, 0);
        }
    };

    for (int cc = 0; cc < 16; cc += 2) {
        iter(cc,     kfA, kfB);
        iter(cc + 1, kfB, kfA);
        asm volatile("s_waitcnt lgkmcnt(0)" ::: "memory");
        __builtin_amdgcn_sched_barrier(0);
        __builtin_amdgcn_s_barrier();
    }

    lsa += __shfl_xor(lsa, 16);
    lsa += __shfl_xor(lsa, 32);
    lsb += __shfl_xor(lsb, 16);
    lsb += __shfl_xor(lsb, 32);
    float inva[4], invb[4];
    #pragma unroll
    for (int r = 0; r < 4; ++r) {
        inva[r] = 1.0f / __shfl(lsa, g * 4 + r);
        invb[r] = 1.0f / __shfl(lsb, g * 4 + r);
    }
    #pragma unroll
    for (int dt = 0; dt < 4; ++dt)
        #pragma unroll
        for (int r = 0; r < 4; ++r) {
            attn[(size_t)(b * 1024 + q0a + g * 4 + r) * 1024 + h * 64 + dt * 16 + j] =
                (bf16)(oa[dt][r] * inva[r]);
            attn[(size_t)(b * 1024 + q0b + g * 4 + r) * 1024 + h * 64 + dt * 16 + j] =
                (bf16)(ob[dt][r] * invb[r]);
        }
}

// ---------------------------------------------------------------------------
extern "C" void kernel_launch(void* const* d_in, const int* in_sizes, int n_in,
                              void* d_out, int out_size, void* d_ws, size_t ws_size,
                              hipStream_t stream)
{
    const float* x    = (const float*)d_in[0];
    const float* ln1g = (const float*)d_in[1];
    const float* ln1b = (const float*)d_in[2];
    const float* wq   = (const float*)d_in[3];
    const float* bq   = (const float*)d_in[4];
    const float* wk   = (const float*)d_in[5];
    const float* bk   = (const float*)d_in[6];
    const float* wv   = (const float*)d_in[7];
    const float* bv   = (const float*)d_in[8];
    const float* wo   = (const float*)d_in[9];
    const float* bo   = (const float*)d_in[10];
    const float* ln2g = (const float*)d_in[11];
    const float* ln2b = (const float*)d_in[12];
    const float* w1   = (const float*)d_in[13];
    const float* b1   = (const float*)d_in[14];
    const float* w2   = (const float*)d_in[15];
    const float* b2   = (const float*)d_in[16];

    char* ws = (char*)d_ws;
    bf16* wqkvT = (bf16*)ws;  ws += (size_t)3072 * 1024 * 2;
    bf16* woT   = (bf16*)ws;  ws += (size_t)1024 * 1024 * 2;
    bf16* w1T   = (bf16*)ws;  ws += (size_t)4096 * 1024 * 2;
    bf16* w2T   = (bf16*)ws;  ws += (size_t)1024 * 4096 * 2;
    float* bqkv = (float*)ws; ws += (size_t)3072 * 4;
    bf16* h     = (bf16*)ws;  ws += (size_t)8192 * 1024 * 2;
    bf16* qkv   = (bf16*)ws;  ws += (size_t)8192 * 3072 * 2;
    bf16* attn  = (bf16*)ws;  ws += (size_t)8192 * 1024 * 2;
    float* outf = (float*)ws; ws += (size_t)8192 * 1024 * 4;
    bf16* m1    = (bf16*)ws;  ws += (size_t)8192 * 4096 * 2;

    (void)hipFuncSetAttribute((const void*)gemm_v7_kernel<0>,
                              hipFuncAttributeMaxDynamicSharedMemorySize, 147456);
    (void)hipFuncSetAttribute((const void*)gemm_v7_kernel<1>,
                              hipFuncAttributeMaxDynamicSharedMemorySize, 147456);
    (void)hipFuncSetAttribute((const void*)gemm_v7_kernel<2>,
                              hipFuncAttributeMaxDynamicSharedMemorySize, 147456);
    (void)hipFuncSetAttribute((const void*)gemm_v7_kernel<3>,
                              hipFuncAttributeMaxDynamicSharedMemorySize, 147456);

    wtrans_kernel<<<dim3(16, 16), 256, 0, stream>>>(wq, wqkvT,                   1024, 1024);
    wtrans_kernel<<<dim3(16, 16), 256, 0, stream>>>(wk, wqkvT + 1024 * 1024,     1024, 1024);
    wtrans_kernel<<<dim3(16, 16), 256, 0, stream>>>(wv, wqkvT + 2 * 1024 * 1024, 1024, 1024);
    wtrans_kernel<<<dim3(16, 16), 256, 0, stream>>>(wo, woT, 1024, 1024);
    wtrans_kernel<<<dim3(64, 16), 256, 0, stream>>>(w1, w1T, 1024, 4096);
    wtrans_kernel<<<dim3(16, 64), 256, 0, stream>>>(w2, w2T, 4096, 1024);
    bias3_kernel<<<12, 256, 0, stream>>>(bq, bk, bv, bqkv);

    // LN1
    ln_kernel<<<8192, 256, 0, stream>>>(x, ln1g, ln1b, h);
    // QKV projection: 32 x 24 = 768 blocks
    gemm_v7_kernel<0><<<768, 512, 147456, stream>>>(h, wqkvT, bqkv, nullptr, qkv, 8192, 3072, 1024);
    // attention (2 dispatches x 512 blocks, 2 q-tiles per wave)
    attn_kernel<<<dim3(8, 64), 256, 0, stream>>>(qkv, attn, 0);
    attn_kernel<<<dim3(8, 64), 256, 0, stream>>>(qkv, attn, 64);
    // O projection + bias + residual(x): 32 x 8 = 256 blocks
    gemm_v7_kernel<1><<<256, 512, 147456, stream>>>(attn, woT, bo, x, outf, 8192, 1024, 1024);
    // LN2
    ln_kernel<<<8192, 256, 0, stream>>>(outf, ln2g, ln2b, h);
    // MLP1: 32 x 32 = 1024 blocks
    gemm_v7_kernel<2><<<1024, 512, 147456, stream>>>(h, w1T, b1, nullptr, m1, 8192, 4096, 1024);
    // MLP2: 32 x 8 = 256 blocks, K=4096
    gemm_v7_kernel<3><<<256, 512, 147456, stream>>>(m1, w2T, b2, outf, (float*)d_out, 8192, 1024, 4096);
}

// Round 10
// 447.719 us; speedup vs baseline: 1.2182x; 1.0049x over previous
//
#include <hip/hip_runtime.h>
#include <cstdint>

typedef __bf16 bf16;
typedef __attribute__((ext_vector_type(8))) __bf16 bf16x8;
typedef __attribute__((ext_vector_type(4))) __bf16 bf16x4;
typedef __attribute__((ext_vector_type(4))) float f32x4;
typedef __attribute__((ext_vector_type(8))) unsigned short u16x8;

#define AS1C(p) ((const __attribute__((address_space(1))) void*)(p))
#define AS3(p)  ((__attribute__((address_space(3))) void*)(p))

__device__ __forceinline__ float gelu_exact(float v) {
    return 0.5f * v * (1.0f + erff(v * 0.7071067811865476f));
}

// ---------------------------------------------------------------------------
// Weight transpose + fp32->bf16 convert: w [K][N] fp32 -> wt [N][K] bf16
// ---------------------------------------------------------------------------
__global__ __launch_bounds__(256, 1) void wtrans_kernel(
    const float* __restrict__ w, bf16* __restrict__ wt, int K, int N)
{
    __shared__ float tile[64][65];
    const int k0 = blockIdx.y * 64, n0 = blockIdx.x * 64;
    const int tid = threadIdx.x;
    {
        const int kl = tid >> 2, nc = (tid & 3) * 16;
        #pragma unroll
        for (int i = 0; i < 4; ++i) {
            const float4 v = *(const float4*)&w[(size_t)(k0 + kl) * N + n0 + nc + i * 4];
            tile[kl][nc + i * 4 + 0] = v.x;
            tile[kl][nc + i * 4 + 1] = v.y;
            tile[kl][nc + i * 4 + 2] = v.z;
            tile[kl][nc + i * 4 + 3] = v.w;
        }
    }
    __syncthreads();
    {
        const int nl = tid >> 2, kc = (tid & 3) * 16;
        #pragma unroll
        for (int i = 0; i < 4; ++i) {
            bf16x4 o4;
            o4[0] = (bf16)tile[kc + i * 4 + 0][nl];
            o4[1] = (bf16)tile[kc + i * 4 + 1][nl];
            o4[2] = (bf16)tile[kc + i * 4 + 2][nl];
            o4[3] = (bf16)tile[kc + i * 4 + 3][nl];
            *(bf16x4*)&wt[(size_t)(n0 + nl) * K + k0 + kc + i * 4] = o4;
        }
    }
}

__global__ void bias3_kernel(const float* __restrict__ a, const float* __restrict__ b,
                             const float* __restrict__ c, float* __restrict__ o)
{
    const int i = blockIdx.x * 256 + threadIdx.x;
    o[i] = (i < 1024) ? a[i] : (i < 2048 ? b[i - 1024] : c[i - 2048]);
}

// ---------------------------------------------------------------------------
// LayerNorm over rows of 1024 fp32 -> bf16. grid 8192 x 256
// ---------------------------------------------------------------------------
__global__ __launch_bounds__(256, 1) void ln_kernel(
    const float* __restrict__ x, const float* __restrict__ gw,
    const float* __restrict__ bw, bf16* __restrict__ out)
{
    const int row = blockIdx.x, tid = threadIdx.x;
    const float4 v = *(const float4*)&x[(size_t)row * 1024 + tid * 4];
    float s = v.x + v.y + v.z + v.w;
    float q = v.x * v.x + v.y * v.y + v.z * v.z + v.w * v.w;
    #pragma unroll
    for (int off = 32; off > 0; off >>= 1) {
        s += __shfl_xor(s, off);
        q += __shfl_xor(q, off);
    }
    __shared__ float red[8];
    if ((tid & 63) == 0) { red[tid >> 6] = s; red[4 + (tid >> 6)] = q; }
    __syncthreads();
    s = red[0] + red[1] + red[2] + red[3];
    q = red[4] + red[5] + red[6] + red[7];
    const float mu = s * (1.f / 1024.f);
    const float rs = rsqrtf(q * (1.f / 1024.f) - mu * mu + 1e-5f);
    const float4 gg = *(const float4*)&gw[tid * 4];
    const float4 bb = *(const float4*)&bw[tid * 4];
    bf16x4 o4;
    o4[0] = (bf16)((v.x - mu) * rs * gg.x + bb.x);
    o4[1] = (bf16)((v.y - mu) * rs * gg.y + bb.y);
    o4[2] = (bf16)((v.z - mu) * rs * gg.z + bb.z);
    o4[3] = (bf16)((v.w - mu) * rs * gg.w + bb.w);
    *(bf16x4*)&out[(size_t)row * 1024 + tid * 4] = o4;
}

// ---------------------------------------------------------------------------
// GEMM v10: m201 geometry. BM=BN=256, 8 waves (2M x 4N), per-wave 128x64,
// BK=64. LDS-read density halved vs v7 (24 ds_read per 64 MFMA per wave):
// per-CU LDS traffic (~2050 cyc) < MFMA work (~2480 cyc) -> compute-bound.
// 2 buffers x 64KB; stage(t+1) at tile top, single vmcnt(0)+barrier at tile
// end (latency hidden under full tile of compute). v7's verified swizzle
// (conflicts=0): read lb ^= (lb>>4)&0x70; source chunk-perm (tid&7)^((tid>>4)&7).
// A-half1 read between the two 32-MFMA clusters caps VGPR (~228).
// EPI: 0 bias->bf16 | 1 bias+res->f32 | 2 gelu->bf16 | 4 raw f32 partial
// (split-K: half = wg / nwg, partial half 0 -> out, half 1 -> res ptr).
// ---------------------------------------------------------------------------
template<int EPI>
__global__ __launch_bounds__(512, 2) void gemm_v10_kernel(
    const bf16* __restrict__ A, const bf16* __restrict__ BT,
    const float* __restrict__ bias, const float* __restrict__ res,
    void* __restrict__ out, int M, int N, int Kstride, int Klen)
{
    constexpr int ABYTES = 256 * 128;   // 32768
    constexpr int BUFB = 512 * 128;     // 65536
    extern __shared__ char lds[];

    const int tid = threadIdx.x;
    const int lane = tid & 63, wid = tid >> 6;
    const int wr = wid >> 2, wc = wid & 3;
    const int j = lane & 15, g = lane >> 4;
    const int skc = ((tid & 7) ^ ((tid >> 4) & 7)) << 3;

    const int nbn = N >> 8;
    const int nwg = (M >> 8) * nbn;
    const int wg = (blockIdx.x & 7) * ((int)gridDim.x >> 3) + (blockIdx.x >> 3);
    const int half = wg / nwg;          // 0 unless split-K
    const int wgl = wg - half * nwg;
    const int bm = (wgl / nbn) << 8;
    const int bn = (wgl % nbn) << 8;
    const int kbase = half * Klen;

    const bf16* srcA[4];
    const bf16* srcB[4];
    #pragma unroll
    for (int ga = 0; ga < 4; ++ga)
        srcA[ga] = A + (size_t)(bm + ga * 64 + (tid >> 3)) * Kstride + kbase + skc;
    #pragma unroll
    for (int gb = 0; gb < 4; ++gb)
        srcB[gb] = BT + (size_t)(bn + gb * 64 + (tid >> 3)) * Kstride + kbase + skc;

    auto stage = [&](char* obuf) {
        #pragma unroll
        for (int ga = 0; ga < 4; ++ga) {
            __builtin_amdgcn_global_load_lds(AS1C(srcA[ga]), AS3(obuf + ga * 8192 + tid * 16), 16, 0, 0);
            srcA[ga] += 64;
        }
        #pragma unroll
        for (int gb = 0; gb < 4; ++gb) {
            __builtin_amdgcn_global_load_lds(AS1C(srcB[gb]), AS3(obuf + ABYTES + gb * 8192 + tid * 16), 16, 0, 0);
            srcB[gb] += 64;
        }
    };
    auto rdA = [&](char* buf, int h, int mf, int ks) {
        const int R = wr * 128 + (h * 4 + mf) * 16 + j;
        uint32_t lb = (uint32_t)(R * 128 + ks * 64 + g * 16);
        lb ^= (lb >> 4) & 0x70u;
        return *(const bf16x8*)(buf + lb);
    };
    auto rdB = [&](char* buf, int nf, int ks) {
        const int R = wc * 64 + nf * 16 + j;
        uint32_t lb = (uint32_t)(R * 128 + ks * 64 + g * 16);
        lb ^= (lb >> 4) & 0x70u;
        return *(const bf16x8*)(buf + ABYTES + lb);
    };

    f32x4 acc[8][4] = {};
    const int NT = Klen >> 6;

    stage(lds);
    asm volatile("s_waitcnt vmcnt(0)" ::: "memory");
    __builtin_amdgcn_s_barrier();

    for (int t = 0; t < NT; ++t) {
        char* buf = lds + (t & 1) * BUFB;

        // B (8) + A-half0 (8) fragment reads
        bf16x8 bfr[4][2], af[4][2];
        #pragma unroll
        for (int nf = 0; nf < 4; ++nf)
            #pragma unroll
            for (int ks = 0; ks < 2; ++ks) bfr[nf][ks] = rdB(buf, nf, ks);
        #pragma unroll
        for (int mf = 0; mf < 4; ++mf)
            #pragma unroll
            for (int ks = 0; ks < 2; ++ks) af[mf][ks] = rdA(buf, 0, mf, ks);
        // stage next tile into the other buffer (released at end of t-1)
        if (t + 1 < NT) stage(lds + ((t + 1) & 1) * BUFB);
        __builtin_amdgcn_sched_barrier(0);
        // cluster 0: A-half0 x B (32 MFMA)
        __builtin_amdgcn_s_setprio(1);
        #pragma unroll
        for (int mf = 0; mf < 4; ++mf)
            #pragma unroll
            for (int nf = 0; nf < 4; ++nf)
                #pragma unroll
                for (int ks = 0; ks < 2; ++ks)
                    acc[mf][nf] = __builtin_amdgcn_mfma_f32_16x16x32_bf16(
                        af[mf][ks], bfr[nf][ks], acc[mf][nf], 0, 0, 0);
        __builtin_amdgcn_s_setprio(0);
        // A-half1 reads (latency covered by other wave's cluster via setprio)
        bf16x8 af1[4][2];
        #pragma unroll
        for (int mf = 0; mf < 4; ++mf)
            #pragma unroll
            for (int ks = 0; ks < 2; ++ks) af1[mf][ks] = rdA(buf, 1, mf, ks);
        __builtin_amdgcn_sched_barrier(0);
        // cluster 1: A-half1 x B (32 MFMA)
        __builtin_amdgcn_s_setprio(1);
        #pragma unroll
        for (int mf = 0; mf < 4; ++mf)
            #pragma unroll
            for (int nf = 0; nf < 4; ++nf)
                #pragma unroll
                for (int ks = 0; ks < 2; ++ks)
                    acc[4 + mf][nf] = __builtin_amdgcn_mfma_f32_16x16x32_bf16(
                        af1[mf][ks], bfr[nf][ks], acc[4 + mf][nf], 0, 0, 0);
        __builtin_amdgcn_s_setprio(0);
        asm volatile("s_waitcnt vmcnt(0)" ::: "memory");
        __builtin_amdgcn_s_barrier();
    }

    const int row0 = bm + wr * 128;
    const int col0 = bn + wc * 64;
    float* po = nullptr;
    if constexpr (EPI == 4)
        po = half ? (float*)res : (float*)out;   // res reused as 2nd partial ptr
    #pragma unroll
    for (int nf = 0; nf < 4; ++nf) {
        const int col = col0 + nf * 16 + j;
        const float bs = (EPI == 4) ? 0.f : bias[col];
        #pragma unroll
        for (int mf = 0; mf < 8; ++mf) {
            #pragma unroll
            for (int r = 0; r < 4; ++r) {
                const int row = row0 + mf * 16 + g * 4 + r;
                float v = acc[mf][nf][r] + bs;
                if constexpr (EPI == 4) {
                    po[(size_t)row * N + col] = v;
                } else if constexpr (EPI == 2) {
                    ((bf16*)out)[(size_t)row * N + col] = (bf16)gelu_exact(v);
                } else if constexpr (EPI == 1) {
                    v += res[(size_t)row * N + col];
                    ((float*)out)[(size_t)row * N + col] = v;
                } else {
                    ((bf16*)out)[(size_t)row * N + col] = (bf16)v;
                }
            }
        }
    }
}

// ---------------------------------------------------------------------------
// Split-K reduce for MLP2: out = gelu(p0+p1+bias) + res (fp32, N=1024).
// ---------------------------------------------------------------------------
__global__ __launch_bounds__(256, 1) void reduce2_kernel(
    const float* __restrict__ p0, const float* __restrict__ p1,
    const float* __restrict__ bias, const float* __restrict__ res,
    float* __restrict__ out)
{
    const size_t i4 = ((size_t)blockIdx.x * 256 + threadIdx.x) * 4;
    const float4 a = *(const float4*)&p0[i4];
    const float4 b = *(const float4*)&p1[i4];
    const float4 r = *(const float4*)&res[i4];
    const float4 bs = *(const float4*)&bias[i4 & 1023];
    float4 o;
    o.x = gelu_exact(a.x + b.x + bs.x) + r.x;
    o.y = gelu_exact(a.y + b.y + bs.y) + r.y;
    o.z = gelu_exact(a.z + b.z + bs.z) + r.z;
    o.w = gelu_exact(a.w + b.w + bs.w) + r.w;
    *(float4*)&out[i4] = o;
}

// ---------------------------------------------------------------------------
// Flash attention v6 (unchanged from round 9 — 2 q-tiles per wave).
// ---------------------------------------------------------------------------
__global__ __launch_bounds__(256, 1) void attn_kernel(
    const bf16* __restrict__ qkv, bf16* __restrict__ attn, int bh_base)
{
    const int tid = threadIdx.x;
    const int lane = tid & 63, wid = tid >> 6;
    const int j = lane & 15, g = lane >> 4;

    const int lin = blockIdx.x + blockIdx.y * 8;
    const int virt = (lin & 7) * 64 + (lin >> 3);
    const int bh = bh_base + (virt >> 3), qp = virt & 7;
    const int b = bh >> 4, h = bh & 15;
    const int q0a = qp * 128 + wid * 16;
    const int q0b = q0a + 64;

    const bf16* Qp = qkv + (size_t)b * 1024 * 3072 + h * 64;
    const bf16* Kp = Qp + 1024;
    const bf16* Vp = Qp + 2048;

    __shared__ __attribute__((aligned(16))) uint32_t vTu[4][64][36];

    const int kp = (tid & 31) * 2;
    const int d0 = (tid >> 5) * 8;
    #pragma unroll
    for (int pb = 0; pb < 2; ++pb) {
        const u16x8 r0 = *(const u16x8*)&Vp[(size_t)(pb * 64 + kp) * 3072 + d0];
        const u16x8 r1 = *(const u16x8*)&Vp[(size_t)(pb * 64 + kp + 1) * 3072 + d0];
        #pragma unroll
        for (int i = 0; i < 8; ++i)
            vTu[pb][d0 + i][kp >> 1] = (uint32_t)r0[i] | ((uint32_t)r1[i] << 16);
    }

    bf16x8 qa0 = *(const bf16x8*)&Qp[(size_t)(q0a + j) * 3072 + g * 8];
    bf16x8 qa1 = *(const bf16x8*)&Qp[(size_t)(q0a + j) * 3072 + 32 + g * 8];
    bf16x8 qb0 = *(const bf16x8*)&Qp[(size_t)(q0b + j) * 3072 + g * 8];
    bf16x8 qb1 = *(const bf16x8*)&Qp[(size_t)(q0b + j) * 3072 + 32 + g * 8];
    #pragma unroll
    for (int e = 0; e < 8; ++e) {
        qa0[e] = (bf16)((float)qa0[e] * 0.03125f);
        qa1[e] = (bf16)((float)qa1[e] * 0.03125f);
        qb0[e] = (bf16)((float)qb0[e] * 0.03125f);
        qb1[e] = (bf16)((float)qb1[e] * 0.03125f);
    }

    const int jperm = (j >> 2) * 8 + (j & 3);

    f32x4 oa[4] = {}, ob[4] = {};
    float mra = -1e30f, lsa = 0.f;
    float mrb = -1e30f, lsb = 0.f;

    bf16x8 kfA[4][2], kfB[4][2];
    #pragma unroll
    for (int t = 0; t < 4; ++t) {
        const int key = (t >> 1) * 32 + jperm + (t & 1) * 4;
        kfA[t][0] = *(const bf16x8*)&Kp[(size_t)key * 3072 + g * 8];
        kfA[t][1] = *(const bf16x8*)&Kp[(size_t)key * 3072 + 32 + g * 8];
    }

    asm volatile("s_waitcnt lgkmcnt(0)" ::: "memory");
    __builtin_amdgcn_s_barrier();

    auto softmax = [&](f32x4 (&s)[4], float& mrun, float& lsum, f32x4 (&o)[4]) {
        float cur = fmaxf(fmaxf(s[0][0], s[0][1]), fmaxf(s[0][2], s[0][3]));
        #pragma unroll
        for (int t = 1; t < 4; ++t)
            cur = fmaxf(cur, fmaxf(fmaxf(s[t][0], s[t][1]), fmaxf(s[t][2], s[t][3])));
        cur = fmaxf(cur, __shfl_xor(cur, 16));
        cur = fmaxf(cur, __shfl_xor(cur, 32));
        if (!__all(cur - mrun <= 8.0f)) {
            const float mnew = fmaxf(mrun, cur);
            const float alpha = __expf(mrun - mnew);
            float al[4];
            #pragma unroll
            for (int r = 0; r < 4; ++r) al[r] = __shfl(alpha, g * 4 + r);
            #pragma unroll
            for (int dt = 0; dt < 4; ++dt)
                #pragma unroll
                for (int r = 0; r < 4; ++r) o[dt][r] *= al[r];
            lsum *= alpha;
            mrun = mnew;
        }
        float ps = 0.f;
        #pragma unroll
        for (int t = 0; t < 4; ++t)
            #pragma unroll
            for (int r = 0; r < 4; ++r) {
                const float p = __expf(s[t][r] - mrun);
                s[t][r] = p;
                ps += p;
            }
        lsum += ps;
    };

    auto iter = [&](int c, bf16x8 (&kf)[4][2], bf16x8 (&kfn)[4][2]) {
        const f32x4 zero = {0.f, 0.f, 0.f, 0.f};
        const bool pfv = (c + 2 < 16);
        const bool pfk = (c + 1 < 16);

        u16x8 r0, r1;
        if (pfv) {
            const size_t vb = (size_t)((c + 2) * 64 + kp) * 3072 + d0;
            r0 = *(const u16x8*)&Vp[vb];
            r1 = *(const u16x8*)&Vp[vb + 3072];
        }

        f32x4 sa[4], sb[4];
        #pragma unroll
        for (int t = 0; t < 4; ++t) {
            sa[t] = __builtin_amdgcn_mfma_f32_16x16x32_bf16(kf[t][0], qa0, zero, 0, 0, 0);
            sb[t] = __builtin_amdgcn_mfma_f32_16x16x32_bf16(kf[t][0], qb0, zero, 0, 0, 0);
            sa[t] = __builtin_amdgcn_mfma_f32_16x16x32_bf16(kf[t][1], qa1, sa[t], 0, 0, 0);
            sb[t] = __builtin_amdgcn_mfma_f32_16x16x32_bf16(kf[t][1], qb1, sb[t], 0, 0, 0);
        }

        if (pfk) {
            #pragma unroll
            for (int t = 0; t < 4; ++t) {
                const int key = (c + 1) * 64 + (t >> 1) * 32 + jperm + (t & 1) * 4;
                kfn[t][0] = *(const bf16x8*)&Kp[(size_t)key * 3072 + g * 8];
                kfn[t][1] = *(const bf16x8*)&Kp[(size_t)key * 3072 + 32 + g * 8];
            }
        }

        softmax(sa, mra, lsa, oa);
        softmax(sb, mrb, lsb, ob);

        bf16x8 paa0, paa1, pab0, pab1;
        #pragma unroll
        for (int r = 0; r < 4; ++r) {
            paa0[r]     = (bf16)sa[0][r];
            paa0[4 + r] = (bf16)sa[1][r];
            paa1[r]     = (bf16)sa[2][r];
            paa1[4 + r] = (bf16)sa[3][r];
            pab0[r]     = (bf16)sb[0][r];
            pab0[4 + r] = (bf16)sb[1][r];
            pab1[r]     = (bf16)sb[2][r];
            pab1[4 + r] = (bf16)sb[3][r];
        }

        if (pfv) {
            const int wb = (c + 2) & 3;
            #pragma unroll
            for (int i = 0; i < 8; ++i)
                vTu[wb][d0 + i][kp >> 1] = (uint32_t)r0[i] | ((uint32_t)r1[i] << 16);
        }

        const int rb = c & 3;
        #pragma unroll
        for (int dt = 0; dt < 4; ++dt) {
            const bf16* vrow = (const bf16*)&vTu[rb][dt * 16 + j][0];
            const bf16x8 vb0 = *(const bf16x8*)(vrow + g * 8);
            const bf16x8 vb1 = *(const bf16x8*)(vrow + 32 + g * 8);
            oa[dt] = __builtin_amdgcn_mfma_f32_16x16x32_bf16(paa0, vb0, oa[dt], 0, 0, 0);
            ob[dt] = __builtin_amdgcn_mfma_f32_16x16x32_bf16(pab0, vb0, ob[dt], 0, 0, 0);
            oa[dt] = __builtin_amdgcn_mfma_f32_16x16x32_bf16(paa1, vb1, oa[dt], 0, 0, 0);
            ob[dt] = __builtin_amdgcn_mfma_f32_16x16x32_bf16(pab1, vb1, ob[dt], 0, 0, 0);
        }
    };

    for (int cc = 0; cc < 16; cc += 2) {
        iter(cc,     kfA, kfB);
        iter(cc + 1, kfB, kfA);
        asm volatile("s_waitcnt lgkmcnt(0)" ::: "memory");
        __builtin_amdgcn_sched_barrier(0);
        __builtin_amdgcn_s_barrier();
    }

    lsa += __shfl_xor(lsa, 16);
    lsa += __shfl_xor(lsa, 32);
    lsb += __shfl_xor(lsb, 16);
    lsb += __shfl_xor(lsb, 32);
    float inva[4], invb[4];
    #pragma unroll
    for (int r = 0; r < 4; ++r) {
        inva[r] = 1.0f / __shfl(lsa, g * 4 + r);
        invb[r] = 1.0f / __shfl(lsb, g * 4 + r);
    }
    #pragma unroll
    for (int dt = 0; dt < 4; ++dt)
        #pragma unroll
        for (int r = 0; r < 4; ++r) {
            attn[(size_t)(b * 1024 + q0a + g * 4 + r) * 1024 + h * 64 + dt * 16 + j] =
                (bf16)(oa[dt][r] * inva[r]);
            attn[(size_t)(b * 1024 + q0b + g * 4 + r) * 1024 + h * 64 + dt * 16 + j] =
                (bf16)(ob[dt][r] * invb[r]);
        }
}

// ---------------------------------------------------------------------------
extern "C" void kernel_launch(void* const* d_in, const int* in_sizes, int n_in,
                              void* d_out, int out_size, void* d_ws, size_t ws_size,
                              hipStream_t stream)
{
    const float* x    = (const float*)d_in[0];
    const float* ln1g = (const float*)d_in[1];
    const float* ln1b = (const float*)d_in[2];
    const float* wq   = (const float*)d_in[3];
    const float* bq   = (const float*)d_in[4];
    const float* wk   = (const float*)d_in[5];
    const float* bk   = (const float*)d_in[6];
    const float* wv   = (const float*)d_in[7];
    const float* bv   = (const float*)d_in[8];
    const float* wo   = (const float*)d_in[9];
    const float* bo   = (const float*)d_in[10];
    const float* ln2g = (const float*)d_in[11];
    const float* ln2b = (const float*)d_in[12];
    const float* w1   = (const float*)d_in[13];
    const float* b1   = (const float*)d_in[14];
    const float* w2   = (const float*)d_in[15];
    const float* b2   = (const float*)d_in[16];

    char* ws = (char*)d_ws;
    bf16* wqkvT = (bf16*)ws;  ws += (size_t)3072 * 1024 * 2;
    bf16* woT   = (bf16*)ws;  ws += (size_t)1024 * 1024 * 2;
    bf16* w1T   = (bf16*)ws;  ws += (size_t)4096 * 1024 * 2;
    bf16* w2T   = (bf16*)ws;  ws += (size_t)1024 * 4096 * 2;
    float* bqkv = (float*)ws; ws += (size_t)3072 * 4;
    bf16* h     = (bf16*)ws;  ws += (size_t)8192 * 1024 * 2;
    bf16* qkv   = (bf16*)ws;  ws += (size_t)8192 * 3072 * 2;   // reused as p0 after attn
    bf16* attn  = (bf16*)ws;  ws += (size_t)8192 * 1024 * 2;
    float* outf = (float*)ws; ws += (size_t)8192 * 1024 * 4;
    bf16* m1    = (bf16*)ws;  ws += (size_t)8192 * 4096 * 2;
    float* p1   = (float*)ws; ws += (size_t)8192 * 1024 * 4;
    float* p0   = (float*)qkv;

    (void)hipFuncSetAttribute((const void*)gemm_v10_kernel<0>,
                              hipFuncAttributeMaxDynamicSharedMemorySize, 131072);
    (void)hipFuncSetAttribute((const void*)gemm_v10_kernel<1>,
                              hipFuncAttributeMaxDynamicSharedMemorySize, 131072);
    (void)hipFuncSetAttribute((const void*)gemm_v10_kernel<2>,
                              hipFuncAttributeMaxDynamicSharedMemorySize, 131072);
    (void)hipFuncSetAttribute((const void*)gemm_v10_kernel<4>,
                              hipFuncAttributeMaxDynamicSharedMemorySize, 131072);

    wtrans_kernel<<<dim3(16, 16), 256, 0, stream>>>(wq, wqkvT,                   1024, 1024);
    wtrans_kernel<<<dim3(16, 16), 256, 0, stream>>>(wk, wqkvT + 1024 * 1024,     1024, 1024);
    wtrans_kernel<<<dim3(16, 16), 256, 0, stream>>>(wv, wqkvT + 2 * 1024 * 1024, 1024, 1024);
    wtrans_kernel<<<dim3(16, 16), 256, 0, stream>>>(wo, woT, 1024, 1024);
    wtrans_kernel<<<dim3(64, 16), 256, 0, stream>>>(w1, w1T, 1024, 4096);
    wtrans_kernel<<<dim3(16, 64), 256, 0, stream>>>(w2, w2T, 4096, 1024);
    bias3_kernel<<<12, 256, 0, stream>>>(bq, bk, bv, bqkv);

    // LN1
    ln_kernel<<<8192, 256, 0, stream>>>(x, ln1g, ln1b, h);
    // QKV projection: 32 x 12 = 384 blocks
    gemm_v10_kernel<0><<<384, 512, 131072, stream>>>(h, wqkvT, bqkv, nullptr, qkv, 8192, 3072, 1024, 1024);
    // attention (2 dispatches x 512 blocks, 2 q-tiles per wave)
    attn_kernel<<<dim3(8, 64), 256, 0, stream>>>(qkv, attn, 0);
    attn_kernel<<<dim3(8, 64), 256, 0, stream>>>(qkv, attn, 64);
    // O projection + bias + residual(x): 32 x 4 = 128 blocks
    gemm_v10_kernel<1><<<128, 512, 131072, stream>>>(attn, woT, bo, x, outf, 8192, 1024, 1024, 1024);
    // LN2
    ln_kernel<<<8192, 256, 0, stream>>>(outf, ln2g, ln2b, h);
    // MLP1: 32 x 16 = 512 blocks
    gemm_v10_kernel<2><<<512, 512, 131072, stream>>>(h, w1T, b1, nullptr, m1, 8192, 4096, 1024, 1024);
    // MLP2 split-K=2: 2 x (32 x 4) = 256 blocks, partials -> p0/p1 (fp32)
    gemm_v10_kernel<4><<<256, 512, 131072, stream>>>(m1, w2T, nullptr, p1, p0, 8192, 1024, 4096, 2048);
    // reduce: d_out = gelu(p0+p1+b2) + outf
    reduce2_kernel<<<8192, 256, 0, stream>>>(p0, p1, b2, outf, (float*)d_out);
}